// Round 1
// 262.200 us; speedup vs baseline: 1.0211x; 1.0211x over previous
//
#include <hip/hip_runtime.h>

typedef unsigned short u16;
typedef __attribute__((ext_vector_type(8))) short short8;
typedef __attribute__((ext_vector_type(4))) float f32x4;

#define D_TOT 2048
#define M_TOT 64
#define H_TOT 128
#define B_TOT 256
#define NG    256      /* number of d-slices (each 8 d's) */
#define XB    131072   /* D_TOT*M_TOT : x row stride per b */
#define W1M   262144   /* H_TOT*D_TOT : w1 stride per m */

__device__ __forceinline__ u16 f2bf(float f) {
  unsigned u = __builtin_bit_cast(unsigned, f);
  u = (u + 0x7fffu + ((u >> 16) & 1u)) >> 16;   // round-to-nearest-even
  return (u16)u;
}
__device__ __forceinline__ float bf2f(u16 v) {
  unsigned u = ((unsigned)v) << 16;
  return __builtin_bit_cast(float, u);
}

// ---------------------------------------------------------------------------
// pw (+ fused p0): pre-pack B'[g][c][h][m] = bf16( w1[m][h][g*8+c] * w2[h][g*8+c] ).
// Pack part: grid 1024 = 64 g-quads (32 d) x 16 h-blocks (8 h), 32 KB tile
// -> ~4.5 blocks/CU (was 2 at 64 KB). Full 128-B w1 d-runs preserved.
// Blocks 1024..1151 do the old p0: ch[h] = b2[h] + sum_d b1[h,d]*w2[h,d].
// ---------------------------------------------------------------------------
__global__ __launch_bounds__(256)
void nlm_pw(const float* __restrict__ w1, const float* __restrict__ w2,
            const float* __restrict__ b1, const float* __restrict__ b2,
            u16* __restrict__ Bp, float* __restrict__ ch) {
  __shared__ __align__(16) u16 tile[32 * 8 * 64];  // [dc][h_l][m] = 32 KB
  const int t = threadIdx.x;

  if (blockIdx.x >= 1024) {  // ---- p0 path (block-uniform branch)
    const int h = blockIdx.x - 1024;
    const float4* pb = (const float4*)(b1 + (size_t)h * D_TOT);
    const float4* pw = (const float4*)(w2 + (size_t)h * D_TOT);
    float s = 0.f;
    for (int i = t; i < D_TOT / 4; i += 256) {
      float4 a = pb[i], w = pw[i];
      s += a.x * w.x + a.y * w.y + a.z * w.z + a.w * w.w;
    }
    float* red = (float*)tile;
    red[t] = s;
    __syncthreads();
    for (int off = 128; off > 0; off >>= 1) {
      if (t < off) red[t] += red[t + off];
      __syncthreads();
    }
    if (t == 0) ch[h] = red[0] + b2[h];
    return;
  }

  const int gq  = blockIdx.x & 63;   // 32-d quad
  const int hb  = blockIdx.x >> 6;   // 16 h-blocks of 8 h
  const int dq0 = gq * 32;

  // 512 tasks: tau = h_l*64 + m  (wave => uniform h_l, m=lane: w2 wave-uniform,
  // LDS b16 writes 2-way conflict only => free)
#pragma unroll
  for (int rep = 0; rep < 2; ++rep) {
    const int tau = rep * 256 + t;
    const int h_l = tau >> 6, m = tau & 63;
    const int h   = hb * 8 + h_l;
    const float* w1p = w1 + (size_t)m * W1M + (size_t)h * D_TOT + dq0;
    const float* w2p = w2 + (size_t)h * D_TOT + dq0;
    u16* dst = tile + h_l * 64 + m;   // + dc*512
#pragma unroll
    for (int q = 0; q < 8; ++q) {      // 8 x float4 = the full 128-B line
      float4 a = *(const float4*)(w1p + q * 4);
      float4 s = *(const float4*)(w2p + q * 4);
      dst[(q * 4 + 0) * 512] = f2bf(a.x * s.x);
      dst[(q * 4 + 1) * 512] = f2bf(a.y * s.y);
      dst[(q * 4 + 2) * 512] = f2bf(a.z * s.z);
      dst[(q * 4 + 3) * 512] = f2bf(a.w * s.w);
    }
  }
  __syncthreads();
  // write out 32 contiguous 1-KB segments (one per dc)
#pragma unroll 4
  for (int dc = 0; dc < 32; ++dc) {
    const int g = gq * 4 + (dc >> 3), c = dc & 7;
    u16* out = Bp + (((size_t)g * 8 + c) * H_TOT + hb * 8) * 64 + t * 2;
    *(ushort2*)out = *(const ushort2*)(tile + dc * 512 + t * 2);
  }
}

// ---------------------------------------------------------------------------
// phase 1: partial[b][g][h] += x * B', K-order = d-major/m-minor.
// chunk c = single d, all 64 m: A-stage = full 256-B x rows, exact-once.
// grid 1024 = 4 b-quarters x 256 g; blockIdx%8 = g%8 -> bq-sharers co-XCD.
// block 512 = 8 waves as 2(bm) x 4(hn); per-wave tile 32b x 32h.
// T14 async-stage: c+1 global loads issued between barrier1(c) and the MFMA
// cluster -> they stay in flight across the MFMA region + barrier2 (register
// loads don't force vmcnt(0) at s_barrier); the convert/LDS-write of c+1
// is the only consumer that waits.
// ---------------------------------------------------------------------------
__global__ __launch_bounds__(512, 4)
void nlm_p1(const float* __restrict__ x, const u16* __restrict__ Bp,
            u16* __restrict__ partial) {
  __shared__ __align__(16) u16 As[64 * 72];    // row b_l, 64 m + 8 pad
  __shared__ __align__(16) u16 Bs[128 * 72];   // row h,   64 m + 8 pad

  const int tid  = threadIdx.x;
  const int g    = blockIdx.x & 255;
  const int bq   = blockIdx.x >> 8;
  const int d0   = g * 8;
  const int lane = tid & 63, wave = tid >> 6;
  const int wm   = wave >> 2;         // 0..1
  const int wn   = wave & 3;          // 0..3
  const int quad = lane >> 4, l16 = lane & 15;

  // A staging: thread -> (b_l = tid>>3, part = tid&7): 32 B of one x row
  const int a_bl = tid >> 3, a_p = tid & 7;
  const float* xrow = x + (size_t)(bq * 64 + a_bl) * XB
                        + (size_t)d0 * M_TOT + a_p * 8;
  // B staging: thread -> (h = tid>>2, qp = tid&3): 32 B of B' chunk
  const int b_h = tid >> 2, b_qp = tid & 3;
  const u16* bsrc = Bp + ((size_t)g * 8 * H_TOT + b_h) * 64 + b_qp * 16;

  f32x4 acc[2][2];
#pragma unroll
  for (int i = 0; i < 2; ++i)
#pragma unroll
    for (int j = 0; j < 2; ++j) acc[i][j] = (f32x4){0.f, 0.f, 0.f, 0.f};

  // ---- prologue: issue c=0 loads
  float4 v0  = *(const float4*)(xrow);
  float4 v1  = *(const float4*)(xrow + 4);
  short8 bv0 = *(const short8*)(bsrc);
  short8 bv1 = *(const short8*)(bsrc + 8);

#pragma unroll
  for (int c = 0; c < 8; ++c) {
    { // ---- convert + LDS-write for c (waits on c's loads only)
      short8 av;
      av[0] = (short)f2bf(v0.x); av[1] = (short)f2bf(v0.y);
      av[2] = (short)f2bf(v0.z); av[3] = (short)f2bf(v0.w);
      av[4] = (short)f2bf(v1.x); av[5] = (short)f2bf(v1.y);
      av[6] = (short)f2bf(v1.z); av[7] = (short)f2bf(v1.w);
      *(short8*)(As + a_bl * 72 + a_p * 8) = av;
      *(short8*)(Bs + b_h * 72 + b_qp * 16)     = bv0;
      *(short8*)(Bs + b_h * 72 + b_qp * 16 + 8) = bv1;
    }
    __syncthreads();
    // ---- issue c+1 loads NOW: latency hides under the MFMA cluster below
    if (c < 7) {
      const float* xp = xrow + (c + 1) * M_TOT;
      v0 = *(const float4*)(xp);
      v1 = *(const float4*)(xp + 4);
      const u16* bp = bsrc + (size_t)(c + 1) * (H_TOT * 64);
      bv0 = *(const short8*)(bp);
      bv1 = *(const short8*)(bp + 8);
    }
#pragma unroll
    for (int s = 0; s < 2; ++s) {
      short8 af[2], bfr[2];
#pragma unroll
      for (int i = 0; i < 2; ++i)
        af[i] = *(const short8*)(As + (wm * 32 + i * 16 + l16) * 72 + s * 32 + quad * 8);
#pragma unroll
      for (int j = 0; j < 2; ++j)
        bfr[j] = *(const short8*)(Bs + (wn * 32 + j * 16 + l16) * 72 + s * 32 + quad * 8);
#pragma unroll
      for (int i = 0; i < 2; ++i)
#pragma unroll
        for (int j = 0; j < 2; ++j)
          acc[i][j] = __builtin_amdgcn_mfma_f32_16x16x32_bf16(af[i], bfr[j], acc[i][j], 0, 0, 0);
    }
    __syncthreads();
  }

  // ---- epilogue: bf16 partials [b][g][h]; plain stores (waves wn 0..3
  // cover full 256-B h-rows -> L2 write-combines full lines)
#pragma unroll
  for (int i = 0; i < 2; ++i)
#pragma unroll
    for (int j = 0; j < 2; ++j) {
      const int hcol = wn * 32 + j * 16 + l16;
#pragma unroll
      for (int r = 0; r < 4; ++r) {
        const int brow = bq * 64 + wm * 32 + i * 16 + quad * 4 + r;
        partial[((size_t)brow * NG + g) * H_TOT + hcol] = f2bf(acc[i][j][r]);
      }
    }
}

// ---------------------------------------------------------------------------
// phase 2: out[b,h] = sum_g partial[b][g][h] + c[h]     grid 256 x 256
// ---------------------------------------------------------------------------
__global__ __launch_bounds__(256)
void nlm_p2(const u16* __restrict__ partial, const float* __restrict__ ch,
            float* __restrict__ out) {
  const int b = blockIdx.x, t = threadIdx.x;
  const int h2   = t & 63;    // ushort2 column: h = 2*h2, 2*h2+1
  const int half = t >> 6;    // 0..3 : g range
  const u16* base = partial + ((size_t)b * NG + half * 64) * H_TOT + 2 * h2;
  float s0 = 0.f, s1 = 0.f;
#pragma unroll 8
  for (int gg = 0; gg < 64; ++gg) {
    unsigned v = __builtin_nontemporal_load((const unsigned*)(base + (size_t)gg * H_TOT));
    s0 += bf2f((u16)(v & 0xffffu));
    s1 += bf2f((u16)(v >> 16));
  }
  __shared__ float red0[256], red1[256];
  red0[t] = s0;
  red1[t] = s1;
  __syncthreads();
  if (t < 64) {
    float a0 = red0[t] + red0[t + 64] + red0[t + 128] + red0[t + 192];
    float a1 = red1[t] + red1[t + 64] + red1[t + 128] + red1[t + 192];
    out[(size_t)b * H_TOT + 2 * t]     = a0 + ch[2 * t];
    out[(size_t)b * H_TOT + 2 * t + 1] = a1 + ch[2 * t + 1];
  }
}

// ---------------------------------------------------------------------------
extern "C" void kernel_launch(void* const* d_in, const int* in_sizes, int n_in,
                              void* d_out, int out_size, void* d_ws, size_t ws_size,
                              hipStream_t stream) {
  const float* x  = (const float*)d_in[0];
  const float* w1 = (const float*)d_in[1];
  const float* b1 = (const float*)d_in[2];
  const float* w2 = (const float*)d_in[3];
  const float* b2 = (const float*)d_in[4];
  float* out = (float*)d_out;

  // ws: partial 16.78 MB | B' 33.55 MB | ch 512 B   (needs ~50.4 MB)
  u16*   partial = (u16*)d_ws;
  u16*   Bp      = (u16*)((char*)d_ws + (size_t)B_TOT * NG * H_TOT * sizeof(u16));
  float* ch      = (float*)((char*)d_ws + (size_t)B_TOT * NG * H_TOT * sizeof(u16)
                                        + (size_t)NG * 8 * H_TOT * 64 * sizeof(u16));

  nlm_pw<<<dim3(1152), dim3(256), 0, stream>>>(w1, w2, b1, b2, Bp, ch);
  nlm_p1<<<dim3(1024), dim3(512), 0, stream>>>(x, Bp, partial);
  nlm_p2<<<dim3(256),  dim3(256), 0, stream>>>(partial, ch, out);
}